// Round 13
// baseline (93.057 us; speedup 1.0000x reference)
//
#include <hip/hip_runtime.h>
#include <math.h>

#define B_ 2
#define S_ 2048
#define D_ 512
#define H_ 8
#define KV_ 4
#define HD_ 64
// qkv row (bf16, stride 768): [q(512) | k(256)] ; V transposed in vt[256][4096]

typedef __attribute__((ext_vector_type(8))) short bf16x8;
typedef __attribute__((ext_vector_type(4))) short bf16x4;
typedef __attribute__((ext_vector_type(4))) float f32x4;
typedef __attribute__((ext_vector_type(16))) float f32x16;
typedef __attribute__((ext_vector_type(4))) unsigned u32x4;

static __device__ __forceinline__ unsigned short f2bf(float f) {
    union { float f; unsigned u; } v; v.f = f;
    unsigned r = v.u + 0x7FFFu + ((v.u >> 16) & 1);
    return (unsigned short)(r >> 16);
}

// ---------------- fp32 -> bf16 pack (x ; wq|wk|wv fused ; wo) + RoPE tables ----------------
__global__ __launch_bounds__(256) void convert_pack_kernel(
    const float* __restrict__ x, const float* __restrict__ wq, const float* __restrict__ wk,
    const float* __restrict__ wv, const float* __restrict__ wo,
    unsigned short* __restrict__ xb, unsigned short* __restrict__ wqkv_b,
    unsigned short* __restrict__ wo_b, float* __restrict__ cosT, float* __restrict__ sinT) {
    if (blockIdx.x >= 2816) {
        int idx = (blockIdx.x - 2816) * 256 + threadIdx.x;   // [0, 65536)
        int s = idx >> 5;
        int i = idx & 31;
        float invf = 1.0f / powf(10000.0f, (float)(2 * i) / (float)HD_);
        double a = (double)((float)s * invf);
        cosT[idx] = (float)cos(a);
        sinT[idx] = (float)sin(a);
        return;
    }
    int i4 = blockIdx.x * blockDim.x + threadIdx.x;
    int e = i4 * 4;
    const float* src;
    unsigned short* dst;
    if (e < 2097152)      { src = x + e;               dst = xb + e; }
    else if (e < 2359296) { src = wq + (e - 2097152);  dst = wqkv_b + (e - 2097152); }
    else if (e < 2490368) { src = wk + (e - 2359296);  dst = wqkv_b + (e - 2097152); }
    else if (e < 2621440) { src = wv + (e - 2490368);  dst = wqkv_b + (e - 2097152); }
    else                  { src = wo + (e - 2621440);  dst = wo_b + (e - 2621440); }
    float4 v = *(const float4*)src;
    bf16x4 o;
    o[0] = (short)f2bf(v.x); o[1] = (short)f2bf(v.y);
    o[2] = (short)f2bf(v.z); o[3] = (short)f2bf(v.w);
    *(bf16x4*)dst = o;
}

// ---------------- bf16 MFMA GEMM body (128x128 tile, BK=32, gload_lds staging) ----------------
// EPI: 0 = fp32 store, 1 = bf16 store, 2 = bf16 store with fused RoPE + RMSNorm (+gain on q)
template <int EPI, typename OutT>
static __device__ __forceinline__ void gemm_body(
    const unsigned short* __restrict__ A, const unsigned short* __restrict__ Bw,
    OutT* __restrict__ Y, int K, int ldy, int bn, int bm,
    unsigned short* As, unsigned short* Bs,
    const float* __restrict__ cosT, const float* __restrict__ sinT,
    const float* __restrict__ gainp) {
    const int t = threadIdx.x;
    const int w = t >> 6, l = t & 63;
    const int g = l >> 4, c = l & 15;
    const int wr = w >> 1, wc = w & 1;
    f32x4 acc[4][4] = {};
    const int lrow = l >> 2;
    const int lcol = (l & 3) * 8;
    for (int k0 = 0; k0 < K; k0 += 32) {
#pragma unroll
        for (int r = 0; r < 2; ++r) {
            int ci = w * 2 + r;
            const unsigned short* ga = A + (size_t)(bm + ci * 16 + lrow) * K + k0 + lcol;
            __builtin_amdgcn_global_load_lds(
                (const __attribute__((address_space(1))) void*)ga,
                (__attribute__((address_space(3))) void*)(As + ci * 512), 16, 0, 0);
            const unsigned short* gb = Bw + (size_t)(bn + ci * 16 + lrow) * K + k0 + lcol;
            __builtin_amdgcn_global_load_lds(
                (const __attribute__((address_space(1))) void*)gb,
                (__attribute__((address_space(3))) void*)(Bs + ci * 512), 16, 0, 0);
        }
        __syncthreads();
        bf16x8 av[4], bv[4];
#pragma unroll
        for (int i = 0; i < 4; ++i)
            av[i] = *(const bf16x8*)(As + (wr * 64 + i * 16 + c) * 32 + g * 8);
#pragma unroll
        for (int j = 0; j < 4; ++j)
            bv[j] = *(const bf16x8*)(Bs + (wc * 64 + j * 16 + c) * 32 + g * 8);
#pragma unroll
        for (int i = 0; i < 4; ++i)
#pragma unroll
            for (int j = 0; j < 4; ++j)
                acc[i][j] = __builtin_amdgcn_mfma_f32_16x16x32_bf16(av[i], bv[j], acc[i][j], 0, 0, 0);
        __syncthreads();
    }
    if constexpr (EPI == 2) {
        const float gv = *gainp;
        const float hscale = ((bn + wc * 64) < 512) ? gv : 1.0f;
#pragma unroll
        for (int i = 0; i < 4; ++i) {
#pragma unroll
            for (int r = 0; r < 4; ++r) {
                int row = bm + wr * 64 + i * 16 + g * 4 + r;
                int s = row & (S_ - 1);
                float c0 = cosT[s * 32 + c],      s0 = sinT[s * 32 + c];
                float c1 = cosT[s * 32 + c + 16], s1 = sinT[s * 32 + c + 16];
                float x1a = acc[i][0][r], x1b = acc[i][1][r];
                float x2a = acc[i][2][r], x2b = acc[i][3][r];
                float y1a = x1a * c0 + x2a * s0, y2a = x2a * c0 - x1a * s0;
                float y1b = x1b * c1 + x2b * s1, y2b = x2b * c1 - x1b * s1;
                float ss = y1a * y1a + y2a * y2a + y1b * y1b + y2b * y2b;
                ss += __shfl_xor(ss, 1, 64);
                ss += __shfl_xor(ss, 2, 64);
                ss += __shfl_xor(ss, 4, 64);
                ss += __shfl_xor(ss, 8, 64);
                float sc = rsqrtf(ss * (1.0f / 64.0f) + 1e-6f) * hscale;
                unsigned short* yr = (unsigned short*)Y + (size_t)row * ldy + bn + wc * 64 + c;
                yr[0]  = f2bf(y1a * sc);
                yr[16] = f2bf(y1b * sc);
                yr[32] = f2bf(y2a * sc);
                yr[48] = f2bf(y2b * sc);
            }
        }
    } else {
#pragma unroll
        for (int i = 0; i < 4; ++i)
#pragma unroll
            for (int j = 0; j < 4; ++j)
#pragma unroll
                for (int r = 0; r < 4; ++r) {
                    int row = bm + wr * 64 + i * 16 + g * 4 + r;
                    int col = bn + wc * 64 + j * 16 + c;
                    float v = acc[i][j][r];
                    if constexpr (EPI == 1)
                        Y[(size_t)row * ldy + col] = (OutT)f2bf(v);
                    else
                        Y[(size_t)row * ldy + col] = v;
                }
    }
}

// ---- fused projections: blocks [0,192) = QK-proj (EPI2) ; [192,256) = V^T-proj (EPI1) ----
__global__ __launch_bounds__(256) void gemm_proj_fused(
    const unsigned short* __restrict__ xb, const unsigned short* __restrict__ wqkv_b,
    unsigned short* __restrict__ qkv, unsigned short* __restrict__ vt,
    const float* __restrict__ cosT, const float* __restrict__ sinT,
    const float* __restrict__ gainp) {
    __shared__ unsigned short As[128 * 32];
    __shared__ unsigned short Bs[128 * 32];
    int bid = blockIdx.x;
    if (bid < 192) {
        int bx = bid % 6, by = bid / 6;
        gemm_body<2, unsigned short>(xb, wqkv_b, qkv, 512, 768, bx * 128, by * 128,
                                     As, Bs, cosT, sinT, gainp);
    } else {
        int b2 = bid - 192;
        int bx = b2 & 31, by = b2 >> 5;
        gemm_body<1, unsigned short>(wqkv_b + 768 * 512, xb, vt, 512, 4096, bx * 128, by * 128,
                                     As, Bs, nullptr, nullptr, nullptr);
    }
}

__global__ __launch_bounds__(256) void gemm_out(
    const unsigned short* __restrict__ A, const unsigned short* __restrict__ Bw,
    float* __restrict__ Y) {
    __shared__ unsigned short As[128 * 32];
    __shared__ unsigned short Bs[128 * 32];
    gemm_body<0, float>(A, Bw, Y, 512, 512, blockIdx.x % 4 * 128, blockIdx.x / 4 * 128,
                        As, Bs, nullptr, nullptr, nullptr);
}

// ---------------- MFMA flash attention v5: barrier-free, all operands direct from L2 ----------------
// Work item = (bh, qt, part): part covers K-tiles [8p, min(8p+8, qt+1)).
// K/V working set (4 MB total) is L2-resident => no LDS staging (m169 lesson).
// Loop has ZERO barriers / ZERO LDS ops; LDS only for the cross-wave epilogue reduce.
__global__ __launch_bounds__(256, 4) void attn_mfma(const unsigned short* __restrict__ qkv,
                                                    const unsigned short* __restrict__ vt,
                                                    unsigned short* __restrict__ aout,
                                                    float* __restrict__ pO,
                                                    float* __restrict__ pL) {
    __shared__ alignas(128) char smem[16896];   // Os f32[64][64] at 0 ; Ls f32[128] at +16384

    const int slot = blockIdx.x >> 4;
    const int bh = blockIdx.x & 15;
    int qt = 31, acc = 0;
    while (acc + (qt >> 3) + 1 <= slot) { acc += (qt >> 3) + 1; --qt; }
    const int part = slot - acc;
    const int np = (qt >> 3) + 1;
    const int kt0 = part * 8;
    const int kt1 = min(kt0 + 8, qt + 1);
    const int hh = bh & 7;
    const int b = bh >> 3;
    const int kvh = hh >> 1;

    const int t = threadIdx.x;
    const int w = t >> 6;
    const int l = t & 63;
    const int wq = w >> 1;   // q-half
    const int wk = w & 1;    // key-half
    const int hl = l >> 5;
    const int l31 = l & 31;

    // ---- Q B-frags from global: B[col=q][k=d] ----
    bf16x8 qf[4];
    {
        const unsigned short* qrow =
            qkv + (size_t)(b * S_ + qt * 64 + wq * 32 + l31) * 768 + hh * 64 + hl * 8;
#pragma unroll
        for (int kd = 0; kd < 4; ++kd)
            qf[kd] = *(const bf16x8*)(qrow + kd * 16);
    }

    const unsigned short* kp = qkv + (size_t)(b * S_) * 768 + 512 + kvh * 64;
    const unsigned short* vp = vt + (size_t)(kvh * 64) * 4096 + b * S_;

    float l_part = 0.0f;
    f32x16 o_acc[2] = {};
    const float LS = 0.125f * 1.4426950408889634f;
    const float SH = 6.0f * 1.4426950408889634f;

    for (int kt = kt0; kt < kt1; ++kt) {
        const bool diag = (kt == qt);
        if (diag && wk > wq) continue;   // wave-uniform, no barriers in loop

        // ---- S^T = mfma(K, Q): A[row=key][k=d], K frags direct from L2 ----
        const unsigned short* krow = kp + (size_t)(kt * 64 + wk * 32 + l31) * 768 + hl * 8;
        f32x16 s_acc = {};
        __builtin_amdgcn_s_setprio(1);
#pragma unroll
        for (int kd = 0; kd < 4; ++kd) {
            bf16x8 afr = *(const bf16x8*)(krow + kd * 16);
            s_acc = __builtin_amdgcn_mfma_f32_32x32x16_bf16(afr, qf[kd], s_acc, 0, 0, 0);
        }
        __builtin_amdgcn_s_setprio(0);

        // ---- V B-frags direct from L2 (independent of softmax) ----
        bf16x8 vf[2][2];
#pragma unroll
        for (int nd = 0; nd < 2; ++nd)
#pragma unroll
            for (int m = 0; m < 2; ++m)
                vf[nd][m] = *(const bf16x8*)(vp + (size_t)(nd * 32 + l31) * 4096 +
                                             kt * 64 + wk * 32 + m * 16 + hl * 8);

        // ---- fixed-shift softmax: p = exp2(s*LS - SH), lane-local ----
        float p[16];
        if (diag && wk == wq) {
#pragma unroll
            for (int idx = 0; idx < 16; ++idx) {
                int keyin = 4 * hl + 8 * (idx >> 2) + (idx & 3);
                float e = exp2f(s_acc[idx] * LS - SH);
                p[idx] = (keyin <= l31) ? e : 0.0f;
            }
        } else {
#pragma unroll
            for (int idx = 0; idx < 16; ++idx)
                p[idx] = exp2f(s_acc[idx] * LS - SH);
        }
#pragma unroll
        for (int idx = 0; idx < 16; ++idx) l_part += p[idx];

        // ---- pack to bf16 pairs + permlane32_swap assembles PV A-frags ----
        unsigned pw[8];
#pragma unroll
        for (int s = 0; s < 4; ++s)
#pragma unroll
            for (int j = 0; j < 2; ++j)
                asm("v_cvt_pk_bf16_f32 %0, %1, %2"
                    : "=v"(pw[s * 2 + j])
                    : "v"(p[4 * s + 2 * j]), "v"(p[4 * s + 2 * j + 1]));
#pragma unroll
        for (int m = 0; m < 2; ++m) {
            asm volatile("v_permlane32_swap_b32 %0, %1" : "+v"(pw[4 * m + 0]), "+v"(pw[4 * m + 2]));
            asm volatile("v_permlane32_swap_b32 %0, %1" : "+v"(pw[4 * m + 1]), "+v"(pw[4 * m + 3]));
        }

        // ---- O += P V ----
        __builtin_amdgcn_s_setprio(1);
#pragma unroll
        for (int m = 0; m < 2; ++m) {
            u32x4 fu = {pw[4 * m + 0], pw[4 * m + 1], pw[4 * m + 2], pw[4 * m + 3]};
            bf16x8 pfr = *(bf16x8*)&fu;
#pragma unroll
            for (int nd = 0; nd < 2; ++nd)
                o_acc[nd] = __builtin_amdgcn_mfma_f32_32x32x16_bf16(pfr, vf[nd][m], o_acc[nd], 0, 0, 0);
        }
        __builtin_amdgcn_s_setprio(0);
    }

    // ---- epilogue: cross-wk reduce via LDS overlay (only LDS use in kernel) ----
    float* Os = (float*)smem;
    float* Ls = (float*)(smem + 16384);
    float lsum = l_part + __shfl_xor(l_part, 32, 64);
    if (hl == 0) Ls[wk * 64 + wq * 32 + l31] = lsum;
    if (wk == 0) {
#pragma unroll
        for (int nd = 0; nd < 2; ++nd)
#pragma unroll
            for (int reg = 0; reg < 16; ++reg) {
                int qrow = 4 * hl + 8 * (reg >> 2) + (reg & 3);
                Os[(wq * 32 + qrow) * 64 + nd * 32 + l31] = o_acc[nd][reg];
            }
    }
    __syncthreads();
    if (wk == 1) {
        if (np == 1) {
            unsigned short* ob = aout + ((size_t)(b * S_ + qt * 64 + wq * 32)) * 512 + hh * 64;
#pragma unroll
            for (int reg = 0; reg < 16; ++reg) {
                int qrow = 4 * hl + 8 * (reg >> 2) + (reg & 3);
                float ltot = Ls[wq * 32 + qrow] + Ls[64 + wq * 32 + qrow];
                float inv = __builtin_amdgcn_rcpf(ltot);
#pragma unroll
                for (int nd = 0; nd < 2; ++nd) {
                    float val = (o_acc[nd][reg] + Os[(wq * 32 + qrow) * 64 + nd * 32 + l31]) * inv;
                    ob[(size_t)qrow * 512 + nd * 32 + l31] = f2bf(val);
                }
            }
        } else {
            float* po = pO + (size_t)blockIdx.x * 4096;
            float* pl = pL + (size_t)blockIdx.x * 64;
#pragma unroll
            for (int reg = 0; reg < 16; ++reg) {
                int qrow = 4 * hl + 8 * (reg >> 2) + (reg & 3);
                float ltot = Ls[wq * 32 + qrow] + Ls[64 + wq * 32 + qrow];
                if (l31 == 0) pl[wq * 32 + qrow] = ltot;
#pragma unroll
                for (int nd = 0; nd < 2; ++nd)
                    po[(wq * 32 + qrow) * 64 + nd * 32 + l31] =
                        o_acc[nd][reg] + Os[(wq * 32 + qrow) * 64 + nd * 32 + l31];
            }
        }
    }
}

// ---------------- combine partials for qt >= 8 (np >= 2) ----------------
__global__ __launch_bounds__(256) void combine_kernel(const float* __restrict__ pO,
                                                      const float* __restrict__ pL,
                                                      unsigned short* __restrict__ aout) {
    const int cid = blockIdx.x;          // 384 = 24 qt values x 16 bh
    const int bh = cid & 15;
    const int qt = 31 - (cid >> 4);      // qt in [8, 31]
    int qq = 31, acc = 0;
    while (qq > qt) { acc += (qq >> 3) + 1; --qq; }
    const int np = (qt >> 3) + 1;
    const int base = acc * 16 + bh;
    const int t = threadIdx.x;
    const int row = t >> 2;
    const int c0 = (t & 3) * 16;
    float l = 0.0f;
    float o[16] = {};
    for (int p = 0; p < np; ++p) {
        const int pid = base + p * 16;
        l += pL[(size_t)pid * 64 + row];
        const float* po = pO + (size_t)pid * 4096 + row * 64 + c0;
#pragma unroll
        for (int j4 = 0; j4 < 4; ++j4) {
            float4 v = *(const float4*)(po + j4 * 4);
            o[j4 * 4 + 0] += v.x; o[j4 * 4 + 1] += v.y;
            o[j4 * 4 + 2] += v.z; o[j4 * 4 + 3] += v.w;
        }
    }
    float inv = __builtin_amdgcn_rcpf(l);
    const int b = bh >> 3, hh = bh & 7;
    unsigned short* ob = aout + (size_t)(b * S_ + qt * 64 + row) * 512 + hh * 64 + c0;
    bf16x4 pk[4];
#pragma unroll
    for (int j4 = 0; j4 < 4; ++j4) {
        pk[j4][0] = (short)f2bf(o[j4 * 4 + 0] * inv);
        pk[j4][1] = (short)f2bf(o[j4 * 4 + 1] * inv);
        pk[j4][2] = (short)f2bf(o[j4 * 4 + 2] * inv);
        pk[j4][3] = (short)f2bf(o[j4 * 4 + 3] * inv);
        *(bf16x4*)(ob + j4 * 4) = pk[j4];
    }
}

extern "C" void kernel_launch(void* const* d_in, const int* in_sizes, int n_in,
                              void* d_out, int out_size, void* d_ws, size_t ws_size,
                              hipStream_t stream) {
    const float* x    = (const float*)d_in[0];
    const float* wq   = (const float*)d_in[1];
    const float* wk   = (const float*)d_in[2];
    const float* wv   = (const float*)d_in[3];
    const float* wo   = (const float*)d_in[4];
    const float* gain = (const float*)d_in[5];
    float* out = (float*)d_out;

    char* ws = (char*)d_ws;
    unsigned short* qkv    = (unsigned short*)(ws);                              // 6 MB: 4096x768
    unsigned short* vt     = (unsigned short*)(ws + (size_t)6  * 1024 * 1024);   // 2 MB: 256x4096
    unsigned short* aout   = (unsigned short*)(ws + (size_t)8  * 1024 * 1024);   // 4 MB: 4096x512
    unsigned short* xb     = (unsigned short*)(ws + (size_t)12 * 1024 * 1024);   // 4 MB
    unsigned short* wqkv_b = (unsigned short*)(ws + (size_t)16 * 1024 * 1024);   // 1 MB
    unsigned short* wo_b   = (unsigned short*)(ws + (size_t)17 * 1024 * 1024);   // 0.5 MB
    float* cosT            = (float*)(ws + (size_t)18 * 1024 * 1024);
    float* sinT            = cosT + (size_t)S_ * (HD_ / 2);
    float* pO              = (float*)(ws + (size_t)32 * 1024 * 1024);            // 1280 x 4096 f32
    float* pL              = pO + (size_t)1280 * 4096;                           // 1280 x 64 f32

    convert_pack_kernel<<<3072, 256, 0, stream>>>(x, wq, wk, wv, wo, xb, wqkv_b, wo_b,
                                                  cosT, sinT);
    gemm_proj_fused<<<256, 256, 0, stream>>>(xb, wqkv_b, qkv, vt, cosT, sinT, gain);
    attn_mfma<<<1280, 256, 0, stream>>>(qkv, vt, aout, pO, pL);
    combine_kernel<<<384, 256, 0, stream>>>(pO, pL, aout);
    gemm_out<<<128, 256, 0, stream>>>(aout, wo_b, out);
}

// Round 15
// 69.797 us; speedup vs baseline: 1.3332x; 1.3332x over previous
//
#include <hip/hip_runtime.h>
#include <math.h>

#define B_ 2
#define S_ 2048
#define D_ 512
#define H_ 8
#define KV_ 4
#define HD_ 64
// qkv row (bf16, stride 768): [q(512) | k(256)] ; V transposed in vt[256][4096]

typedef __attribute__((ext_vector_type(8))) short bf16x8;
typedef __attribute__((ext_vector_type(4))) short bf16x4;
typedef __attribute__((ext_vector_type(4))) float f32x4;
typedef __attribute__((ext_vector_type(16))) float f32x16;
typedef __attribute__((ext_vector_type(4))) unsigned u32x4;

static __device__ __forceinline__ unsigned short f2bf(float f) {
    union { float f; unsigned u; } v; v.f = f;
    unsigned r = v.u + 0x7FFFu + ((v.u >> 16) & 1);
    return (unsigned short)(r >> 16);
}

// ---------------- fp32 -> bf16 pack (x ; wq|wk|wv fused ; wo) + RoPE tables ----------------
__global__ __launch_bounds__(256) void convert_pack_kernel(
    const float* __restrict__ x, const float* __restrict__ wq, const float* __restrict__ wk,
    const float* __restrict__ wv, const float* __restrict__ wo,
    unsigned short* __restrict__ xb, unsigned short* __restrict__ wqkv_b,
    unsigned short* __restrict__ wo_b, float* __restrict__ cosT, float* __restrict__ sinT) {
    if (blockIdx.x >= 2816) {
        int idx = (blockIdx.x - 2816) * 256 + threadIdx.x;   // [0, 65536)
        int s = idx >> 5;
        int i = idx & 31;
        float invf = 1.0f / powf(10000.0f, (float)(2 * i) / (float)HD_);
        double a = (double)((float)s * invf);
        cosT[idx] = (float)cos(a);
        sinT[idx] = (float)sin(a);
        return;
    }
    int i4 = blockIdx.x * blockDim.x + threadIdx.x;
    int e = i4 * 4;
    const float* src;
    unsigned short* dst;
    if (e < 2097152)      { src = x + e;               dst = xb + e; }
    else if (e < 2359296) { src = wq + (e - 2097152);  dst = wqkv_b + (e - 2097152); }
    else if (e < 2490368) { src = wk + (e - 2359296);  dst = wqkv_b + (e - 2097152); }
    else if (e < 2621440) { src = wv + (e - 2490368);  dst = wqkv_b + (e - 2097152); }
    else                  { src = wo + (e - 2621440);  dst = wo_b + (e - 2621440); }
    float4 v = *(const float4*)src;
    bf16x4 o;
    o[0] = (short)f2bf(v.x); o[1] = (short)f2bf(v.y);
    o[2] = (short)f2bf(v.z); o[3] = (short)f2bf(v.w);
    *(bf16x4*)dst = o;
}

// ------- bf16 MFMA GEMM body (128x128 tile, BK=32, 2-phase dbuf gload_lds staging) -------
// As/Bs are 2x(128*32)-element double buffers. Loop kept NON-unrolled (#pragma unroll 1) and
// an explicit vmcnt(0) drain precedes the bottom barrier: the fully-unrolled variant (r14)
// miscompiled (absmax 4e-2) — suspected waitcnt-insertion miss for LDS-DMA across barriers.
// EPI: 0 = fp32 store, 1 = bf16 store, 2 = bf16 store with fused RoPE + RMSNorm (+gain on q)
template <int EPI, typename OutT>
static __device__ __forceinline__ void gemm_body(
    const unsigned short* __restrict__ A, const unsigned short* __restrict__ Bw,
    OutT* __restrict__ Y, int K, int ldy, int bn, int bm,
    unsigned short* As, unsigned short* Bs,
    const float* __restrict__ cosT, const float* __restrict__ sinT,
    const float* __restrict__ gainp) {
    const int t = threadIdx.x;
    const int w = t >> 6, l = t & 63;
    const int g = l >> 4, c = l & 15;
    const int wr = w >> 1, wc = w & 1;
    f32x4 acc[4][4] = {};
    const int lrow = l >> 2;
    const int lcol = (l & 3) * 8;

    auto stage = [&](int k0, int bufi) {
#pragma unroll
        for (int r = 0; r < 2; ++r) {
            int ci = w * 2 + r;
            const unsigned short* ga = A + (size_t)(bm + ci * 16 + lrow) * K + k0 + lcol;
            __builtin_amdgcn_global_load_lds(
                (const __attribute__((address_space(1))) void*)ga,
                (__attribute__((address_space(3))) void*)(As + bufi * 4096 + ci * 512), 16, 0, 0);
            const unsigned short* gb = Bw + (size_t)(bn + ci * 16 + lrow) * K + k0 + lcol;
            __builtin_amdgcn_global_load_lds(
                (const __attribute__((address_space(1))) void*)gb,
                (__attribute__((address_space(3))) void*)(Bs + bufi * 4096 + ci * 512), 16, 0, 0);
        }
    };

    stage(0, 0);
    asm volatile("s_waitcnt vmcnt(0)" ::: "memory");
    __syncthreads();   // buf0 ready
    int buf = 0;
#pragma unroll 1
    for (int k0 = 0; k0 < K; k0 += 32) {
        if (k0 + 32 < K) stage(k0 + 32, buf ^ 1);   // prefetch next tile into other buffer
        const unsigned short* Ab = As + buf * 4096;
        const unsigned short* Bb = Bs + buf * 4096;
        bf16x8 av[4], bv[4];
#pragma unroll
        for (int i = 0; i < 4; ++i)
            av[i] = *(const bf16x8*)(Ab + (wr * 64 + i * 16 + c) * 32 + g * 8);
#pragma unroll
        for (int j = 0; j < 4; ++j)
            bv[j] = *(const bf16x8*)(Bb + (wc * 64 + j * 16 + c) * 32 + g * 8);
#pragma unroll
        for (int i = 0; i < 4; ++i)
#pragma unroll
            for (int j = 0; j < 4; ++j)
                acc[i][j] = __builtin_amdgcn_mfma_f32_16x16x32_bf16(av[i], bv[j], acc[i][j], 0, 0, 0);
        asm volatile("s_waitcnt vmcnt(0)" ::: "memory");   // next tile's DMA drained
        __syncthreads();   // + all waves done reading buf
        buf ^= 1;
    }
    if constexpr (EPI == 2) {
        const float gv = *gainp;
        const float hscale = ((bn + wc * 64) < 512) ? gv : 1.0f;
#pragma unroll
        for (int i = 0; i < 4; ++i) {
#pragma unroll
            for (int r = 0; r < 4; ++r) {
                int row = bm + wr * 64 + i * 16 + g * 4 + r;
                int s = row & (S_ - 1);
                float c0 = cosT[s * 32 + c],      s0 = sinT[s * 32 + c];
                float c1 = cosT[s * 32 + c + 16], s1 = sinT[s * 32 + c + 16];
                float x1a = acc[i][0][r], x1b = acc[i][1][r];
                float x2a = acc[i][2][r], x2b = acc[i][3][r];
                float y1a = x1a * c0 + x2a * s0, y2a = x2a * c0 - x1a * s0;
                float y1b = x1b * c1 + x2b * s1, y2b = x2b * c1 - x1b * s1;
                float ss = y1a * y1a + y2a * y2a + y1b * y1b + y2b * y2b;
                ss += __shfl_xor(ss, 1, 64);
                ss += __shfl_xor(ss, 2, 64);
                ss += __shfl_xor(ss, 4, 64);
                ss += __shfl_xor(ss, 8, 64);
                float sc = rsqrtf(ss * (1.0f / 64.0f) + 1e-6f) * hscale;
                unsigned short* yr = (unsigned short*)Y + (size_t)row * ldy + bn + wc * 64 + c;
                yr[0]  = f2bf(y1a * sc);
                yr[16] = f2bf(y1b * sc);
                yr[32] = f2bf(y2a * sc);
                yr[48] = f2bf(y2b * sc);
            }
        }
    } else {
#pragma unroll
        for (int i = 0; i < 4; ++i)
#pragma unroll
            for (int j = 0; j < 4; ++j)
#pragma unroll
                for (int r = 0; r < 4; ++r) {
                    int row = bm + wr * 64 + i * 16 + g * 4 + r;
                    int col = bn + wc * 64 + j * 16 + c;
                    float v = acc[i][j][r];
                    if constexpr (EPI == 1)
                        Y[(size_t)row * ldy + col] = (OutT)f2bf(v);
                    else
                        Y[(size_t)row * ldy + col] = v;
                }
    }
}

// ---- fused projections: blocks [0,192) = QK-proj (EPI2) ; [192,256) = V^T-proj (EPI1) ----
__global__ __launch_bounds__(256) void gemm_proj_fused(
    const unsigned short* __restrict__ xb, const unsigned short* __restrict__ wqkv_b,
    unsigned short* __restrict__ qkv, unsigned short* __restrict__ vt,
    const float* __restrict__ cosT, const float* __restrict__ sinT,
    const float* __restrict__ gainp) {
    __shared__ unsigned short As[2 * 128 * 32];
    __shared__ unsigned short Bs[2 * 128 * 32];
    int bid = blockIdx.x;
    if (bid < 192) {
        int bx = bid % 6, by = bid / 6;
        gemm_body<2, unsigned short>(xb, wqkv_b, qkv, 512, 768, bx * 128, by * 128,
                                     As, Bs, cosT, sinT, gainp);
    } else {
        int b2 = bid - 192;
        int bx = b2 & 31, by = b2 >> 5;
        gemm_body<1, unsigned short>(wqkv_b + 768 * 512, xb, vt, 512, 4096, bx * 128, by * 128,
                                     As, Bs, nullptr, nullptr, nullptr);
    }
}

__global__ __launch_bounds__(256) void gemm_out(
    const unsigned short* __restrict__ A, const unsigned short* __restrict__ Bw,
    float* __restrict__ Y) {
    __shared__ unsigned short As[2 * 128 * 32];
    __shared__ unsigned short Bs[2 * 128 * 32];
    gemm_body<0, float>(A, Bw, Y, 512, 512, blockIdx.x % 4 * 128, blockIdx.x / 4 * 128,
                        As, Bs, nullptr, nullptr, nullptr);
}

// ---------------- MFMA flash attention v4: key-split PS=8 + backfill (r7 version) ----------------
#define SWZF(row) ((((row) + ((row) >> 3)) & 7) << 4)

__global__ __launch_bounds__(256, 3) void attn_mfma(const unsigned short* __restrict__ qkv,
                                                    const unsigned short* __restrict__ vt,
                                                    unsigned short* __restrict__ aout,
                                                    float* __restrict__ pO,
                                                    float* __restrict__ pL) {
    __shared__ alignas(128) char smem[32768];

    const int slot = blockIdx.x >> 4;
    const int bh = blockIdx.x & 15;
    int qt = 31, acc = 0;
    while (acc + (qt >> 3) + 1 <= slot) { acc += (qt >> 3) + 1; --qt; }
    const int part = slot - acc;
    const int np = (qt >> 3) + 1;
    const int kt0 = part * 8;
    const int kt1 = min(kt0 + 8, qt + 1);
    const int hh = bh & 7;
    const int b = bh >> 3;
    const int kvh = hh >> 1;

    const int t = threadIdx.x;
    const int w = t >> 6;
    const int l = t & 63;
    const int wq = w >> 1;
    const int wk = w & 1;
    const int hl = l >> 5;
    const int l31 = l & 31;

    const int row0 = t >> 3;
    const int row1 = (256 + t) >> 3;
    const int seg = l & 7;
    const int off0 = (seg * 16) ^ SWZF(row0);
    const int off1 = (seg * 16) ^ SWZF(row1);
    const int cb0 = w * 1024;
    const int cb1 = 4096 + w * 1024;

    bf16x8 qf[4];
    {
        const unsigned short* qrow =
            qkv + (size_t)(b * S_ + qt * 64 + wq * 32 + l31) * 768 + hh * 64 + hl * 8;
#pragma unroll
        for (int kd = 0; kd < 4; ++kd)
            qf[kd] = *(const bf16x8*)(qrow + kd * 16);
    }

    const char* kb = (const char*)qkv + ((size_t)(b * S_)) * 1536 + 1024 + kvh * 128;
    const char* vb = (const char*)vt + ((size_t)(kvh * 64)) * 8192 + (size_t)(b * S_) * 2;

#define STAGE(kt_, bufi_)                                                                        \
    do {                                                                                         \
        const char* ks_ = kb + (size_t)(kt_) * 64 * 1536;                                        \
        const char* vs_ = vb + (size_t)(kt_) * 128;                                              \
        char* kd_ = smem + (bufi_)*8192;                                                         \
        char* vd_ = smem + 16384 + (bufi_)*8192;                                                 \
        __builtin_amdgcn_global_load_lds(                                                        \
            (const __attribute__((address_space(1))) void*)(ks_ + (size_t)row0 * 1536 + off0),   \
            (__attribute__((address_space(3))) void*)(kd_ + cb0), 16, 0, 0);                     \
        __builtin_amdgcn_global_load_lds(                                                        \
            (const __attribute__((address_space(1))) void*)(ks_ + (size_t)row1 * 1536 + off1),   \
            (__attribute__((address_space(3))) void*)(kd_ + cb1), 16, 0, 0);                     \
        __builtin_amdgcn_global_load_lds(                                                        \
            (const __attribute__((address_space(1))) void*)(vs_ + (size_t)row0 * 8192 + off0),   \
            (__attribute__((address_space(3))) void*)(vd_ + cb0), 16, 0, 0);                     \
        __builtin_amdgcn_global_load_lds(                                                        \
            (const __attribute__((address_space(1))) void*)(vs_ + (size_t)row1 * 8192 + off1),   \
            (__attribute__((address_space(3))) void*)(vd_ + cb1), 16, 0, 0);                     \
    } while (0)

    STAGE(kt0, 0);
    __syncthreads();

    float l_part = 0.0f;
    f32x16 o_acc[2] = {};
    const float LS = 0.125f * 1.4426950408889634f;
    const float SH = 6.0f * 1.4426950408889634f;

    int buf = 0;
    for (int kt = kt0; kt < kt1; ++kt) {
        if (kt + 1 < kt1) STAGE(kt + 1, buf ^ 1);
        const char* KsB = smem + buf * 8192;
        const char* VtB = smem + 16384 + buf * 8192;
        const bool diag = (kt == qt);

        if (!(diag && wk > wq)) {
            f32x16 s_acc = {};
            {
                int arow = wk * 32 + l31;
                int af = SWZF(arow);
                __builtin_amdgcn_s_setprio(1);
#pragma unroll
                for (int kd = 0; kd < 4; ++kd) {
                    bf16x8 afr = *(const bf16x8*)(KsB + arow * 128 + ((kd * 32 + hl * 16) ^ af));
                    s_acc = __builtin_amdgcn_mfma_f32_32x32x16_bf16(afr, qf[kd], s_acc, 0, 0, 0);
                }
                __builtin_amdgcn_s_setprio(0);
            }
            bf16x8 vf[2][2];
#pragma unroll
            for (int nd = 0; nd < 2; ++nd) {
                int vr = nd * 32 + l31;
                int fv = SWZF(vr);
#pragma unroll
                for (int m = 0; m < 2; ++m)
                    vf[nd][m] = *(const bf16x8*)(VtB + vr * 128 + ((wk * 64 + m * 32 + hl * 16) ^ fv));
            }
            float p[16];
            if (diag && wk == wq) {
#pragma unroll
                for (int idx = 0; idx < 16; ++idx) {
                    int keyin = 4 * hl + 8 * (idx >> 2) + (idx & 3);
                    float e = exp2f(s_acc[idx] * LS - SH);
                    p[idx] = (keyin <= l31) ? e : 0.0f;
                }
            } else {
#pragma unroll
                for (int idx = 0; idx < 16; ++idx)
                    p[idx] = exp2f(s_acc[idx] * LS - SH);
            }
#pragma unroll
            for (int idx = 0; idx < 16; ++idx) l_part += p[idx];
            unsigned pw[8];
#pragma unroll
            for (int s = 0; s < 4; ++s)
#pragma unroll
                for (int j = 0; j < 2; ++j)
                    asm("v_cvt_pk_bf16_f32 %0, %1, %2"
                        : "=v"(pw[s * 2 + j])
                        : "v"(p[4 * s + 2 * j]), "v"(p[4 * s + 2 * j + 1]));
#pragma unroll
            for (int m = 0; m < 2; ++m) {
                asm volatile("v_permlane32_swap_b32 %0, %1" : "+v"(pw[4 * m + 0]), "+v"(pw[4 * m + 2]));
                asm volatile("v_permlane32_swap_b32 %0, %1" : "+v"(pw[4 * m + 1]), "+v"(pw[4 * m + 3]));
            }
            __builtin_amdgcn_s_setprio(1);
#pragma unroll
            for (int m = 0; m < 2; ++m) {
                u32x4 fu = {pw[4 * m + 0], pw[4 * m + 1], pw[4 * m + 2], pw[4 * m + 3]};
                bf16x8 pfr = *(bf16x8*)&fu;
#pragma unroll
                for (int nd = 0; nd < 2; ++nd)
                    o_acc[nd] = __builtin_amdgcn_mfma_f32_32x32x16_bf16(pfr, vf[nd][m], o_acc[nd], 0, 0, 0);
            }
            __builtin_amdgcn_s_setprio(0);
        }
        __syncthreads();
        buf ^= 1;
    }
#undef STAGE

    float* Os = (float*)smem;
    float* Ls = (float*)(smem + 16384);
    float lsum = l_part + __shfl_xor(l_part, 32, 64);
    if (hl == 0) Ls[wk * 64 + wq * 32 + l31] = lsum;
    if (wk == 0) {
#pragma unroll
        for (int nd = 0; nd < 2; ++nd)
#pragma unroll
            for (int reg = 0; reg < 16; ++reg) {
                int qrow = 4 * hl + 8 * (reg >> 2) + (reg & 3);
                Os[(wq * 32 + qrow) * 64 + nd * 32 + l31] = o_acc[nd][reg];
            }
    }
    __syncthreads();
    if (wk == 1) {
        if (np == 1) {
            unsigned short* ob = aout + ((size_t)(b * S_ + qt * 64 + wq * 32)) * 512 + hh * 64;
#pragma unroll
            for (int reg = 0; reg < 16; ++reg) {
                int qrow = 4 * hl + 8 * (reg >> 2) + (reg & 3);
                float ltot = Ls[wq * 32 + qrow] + Ls[64 + wq * 32 + qrow];
                float inv = __builtin_amdgcn_rcpf(ltot);
#pragma unroll
                for (int nd = 0; nd < 2; ++nd) {
                    float val = (o_acc[nd][reg] + Os[(wq * 32 + qrow) * 64 + nd * 32 + l31]) * inv;
                    ob[(size_t)qrow * 512 + nd * 32 + l31] = f2bf(val);
                }
            }
        } else {
            float* po = pO + (size_t)blockIdx.x * 4096;
            float* pl = pL + (size_t)blockIdx.x * 64;
#pragma unroll
            for (int reg = 0; reg < 16; ++reg) {
                int qrow = 4 * hl + 8 * (reg >> 2) + (reg & 3);
                float ltot = Ls[wq * 32 + qrow] + Ls[64 + wq * 32 + qrow];
                if (l31 == 0) pl[wq * 32 + qrow] = ltot;
#pragma unroll
                for (int nd = 0; nd < 2; ++nd)
                    po[(wq * 32 + qrow) * 64 + nd * 32 + l31] =
                        o_acc[nd][reg] + Os[(wq * 32 + qrow) * 64 + nd * 32 + l31];
            }
        }
    }
}

// ---------------- combine partials for qt >= 8 (np >= 2) ----------------
__global__ __launch_bounds__(256) void combine_kernel(const float* __restrict__ pO,
                                                      const float* __restrict__ pL,
                                                      unsigned short* __restrict__ aout) {
    const int cid = blockIdx.x;          // 384 = 24 qt values x 16 bh
    const int bh = cid & 15;
    const int qt = 31 - (cid >> 4);      // qt in [8, 31]
    int qq = 31, acc = 0;
    while (qq > qt) { acc += (qq >> 3) + 1; --qq; }
    const int np = (qt >> 3) + 1;
    const int base = acc * 16 + bh;
    const int t = threadIdx.x;
    const int row = t >> 2;
    const int c0 = (t & 3) * 16;
    float l = 0.0f;
    float o[16] = {};
    for (int p = 0; p < np; ++p) {
        const int pid = base + p * 16;
        l += pL[(size_t)pid * 64 + row];
        const float* po = pO + (size_t)pid * 4096 + row * 64 + c0;
#pragma unroll
        for (int j4 = 0; j4 < 4; ++j4) {
            float4 v = *(const float4*)(po + j4 * 4);
            o[j4 * 4 + 0] += v.x; o[j4 * 4 + 1] += v.y;
            o[j4 * 4 + 2] += v.z; o[j4 * 4 + 3] += v.w;
        }
    }
    float inv = __builtin_amdgcn_rcpf(l);
    const int b = bh >> 3, hh = bh & 7;
    unsigned short* ob = aout + (size_t)(b * S_ + qt * 64 + row) * 512 + hh * 64 + c0;
    bf16x4 pk[4];
#pragma unroll
    for (int j4 = 0; j4 < 4; ++j4) {
        pk[j4][0] = (short)f2bf(o[j4 * 4 + 0] * inv);
        pk[j4][1] = (short)f2bf(o[j4 * 4 + 1] * inv);
        pk[j4][2] = (short)f2bf(o[j4 * 4 + 2] * inv);
        pk[j4][3] = (short)f2bf(o[j4 * 4 + 3] * inv);
        *(bf16x4*)(ob + j4 * 4) = pk[j4];
    }
}

extern "C" void kernel_launch(void* const* d_in, const int* in_sizes, int n_in,
                              void* d_out, int out_size, void* d_ws, size_t ws_size,
                              hipStream_t stream) {
    const float* x    = (const float*)d_in[0];
    const float* wq   = (const float*)d_in[1];
    const float* wk   = (const float*)d_in[2];
    const float* wv   = (const float*)d_in[3];
    const float* wo   = (const float*)d_in[4];
    const float* gain = (const float*)d_in[5];
    float* out = (float*)d_out;

    char* ws = (char*)d_ws;
    unsigned short* qkv    = (unsigned short*)(ws);                              // 6 MB: 4096x768
    unsigned short* vt     = (unsigned short*)(ws + (size_t)6  * 1024 * 1024);   // 2 MB: 256x4096
    unsigned short* aout   = (unsigned short*)(ws + (size_t)8  * 1024 * 1024);   // 4 MB: 4096x512
    unsigned short* xb     = (unsigned short*)(ws + (size_t)12 * 1024 * 1024);   // 4 MB
    unsigned short* wqkv_b = (unsigned short*)(ws + (size_t)16 * 1024 * 1024);   // 1 MB
    unsigned short* wo_b   = (unsigned short*)(ws + (size_t)17 * 1024 * 1024);   // 0.5 MB
    float* cosT            = (float*)(ws + (size_t)18 * 1024 * 1024);
    float* sinT            = cosT + (size_t)S_ * (HD_ / 2);
    float* pO              = (float*)(ws + (size_t)32 * 1024 * 1024);            // 1280 x 4096 f32
    float* pL              = pO + (size_t)1280 * 4096;                           // 1280 x 64 f32

    convert_pack_kernel<<<3072, 256, 0, stream>>>(x, wq, wk, wv, wo, xb, wqkv_b, wo_b,
                                                  cosT, sinT);
    gemm_proj_fused<<<256, 256, 0, stream>>>(xb, wqkv_b, qkv, vt, cosT, sinT, gain);
    attn_mfma<<<1280, 256, 0, stream>>>(qkv, vt, aout, pO, pL);
    combine_kernel<<<384, 256, 0, stream>>>(pO, pL, aout);
    gemm_out<<<128, 256, 0, stream>>>(aout, wo_b, out);
}